// Round 5
// baseline (1017.878 us; speedup 1.0000x reference)
//
#include <hip/hip_runtime.h>
#include <hip/hip_bf16.h>
#include <cstdint>
#include <cstddef>

#define N_NODES_C 19385
#define N_EDGES_C 1200000
#define GNN_C 256
#define HID_C 512
#define RANK_C 512
#define NCLS_C 3
#define NGENES_C 6640
#define NBLK_C 6
#define B_C 256
#define LN_EPS 1e-5f

typedef short bf8v __attribute__((ext_vector_type(8)));
typedef float f4v __attribute__((ext_vector_type(4)));
typedef unsigned short ushort_t;

__device__ __forceinline__ float bfu2f(unsigned short u) {
  union { unsigned int i; float f; } c; c.i = ((unsigned)u) << 16; return c.f;
}
__device__ __forceinline__ unsigned short f2bfu(float v) {
  union { float f; unsigned u; } c; c.f = v;
  unsigned r = c.u + 0x7FFFu + ((c.u >> 16) & 1u);
  return (unsigned short)(r >> 16);
}
__device__ __forceinline__ float gelu_tanh(float v) {
  const float x3 = v * v * v;
  return 0.5f * v * (1.f + tanhf(0.7978845608028654f * (v + 0.044715f * x3)));
}

// ---------------- batched fp32 -> bf16 convert ----------------

struct CvtSeg { const float* s; unsigned short* d; long long n; };
struct CvtArgs { CvtSeg seg[6]; int nseg; };

__global__ __launch_bounds__(256) void multicvt_kernel(CvtArgs a) {
  for (int sg = 0; sg < a.nseg; ++sg) {
    const float4* s = reinterpret_cast<const float4*>(a.seg[sg].s);
    unsigned short* d = a.seg[sg].d;
    const long long n4 = a.seg[sg].n >> 2;
    for (long long i = blockIdx.x * 256 + threadIdx.x; i < n4;
         i += (long long)gridDim.x * 256) {
      float4 v = s[i];
      ushort4 o;
      o.x = f2bfu(v.x); o.y = f2bfu(v.y); o.z = f2bfu(v.z); o.w = f2bfu(v.w);
      *reinterpret_cast<ushort4*>(d + i * 4) = o;
    }
  }
}

// ---------------- CSR build ----------------

__global__ __launch_bounds__(256) void hist_kernel(const int* __restrict__ dst,
                                                   int* __restrict__ cnt, int E) {
  int i = blockIdx.x * 256 + threadIdx.x;
  if (i < E) atomicAdd(&cnt[dst[i]], 1);
}

__global__ __launch_bounds__(1024) void scan_kernel(const int* __restrict__ cnt,
                                                    int* __restrict__ off, int n) {
  __shared__ int sums[1024];
  const int t = threadIdx.x;
  const int CH = (n + 1023) >> 10;
  const int base = t * CH;
  int s = 0;
  for (int i = 0; i < CH; ++i) {
    int idx = base + i;
    if (idx < n) s += cnt[idx];
  }
  sums[t] = s;
  __syncthreads();
  for (int d = 1; d < 1024; d <<= 1) {
    int v = (t >= d) ? sums[t - d] : 0;
    __syncthreads();
    sums[t] += v;
    __syncthreads();
  }
  int run = (t == 0) ? 0 : sums[t - 1];
  for (int i = 0; i < CH; ++i) {
    int idx = base + i;
    if (idx < n) { off[idx] = run; run += cnt[idx]; }
  }
  if (t == 0) off[n] = sums[1023];
}

__global__ __launch_bounds__(256) void fill_kernel(const int* __restrict__ src,
                                                   const int* __restrict__ dst,
                                                   const float* __restrict__ ew,
                                                   const int* __restrict__ off,
                                                   int* __restrict__ cur,
                                                   int* __restrict__ bsrc,
                                                   float* __restrict__ bw, int E) {
  int i = blockIdx.x * 256 + threadIdx.x;
  if (i < E) {
    int d = dst[i];
    int p = atomicAdd(&cur[d], 1);
    int q = off[d] + p;
    bsrc[q] = src[i] * GNN_C;
    bw[q] = ew[i];
  }
}

// ---------------- edge aggregation ----------------

__global__ __launch_bounds__(256) void agg_full_kernel(const int* __restrict__ bsrc,
                                                       const float* __restrict__ bw,
                                                       const int* __restrict__ off,
                                                       const unsigned short* __restrict__ x,
                                                       unsigned short* __restrict__ aggbf) {
  __shared__ int ss[64];
  __shared__ float sw[64];
  const int n = blockIdx.x;
  const int t = threadIdx.x;
  const int s0 = off[n], s1 = off[n + 1];
  float acc = 0.f;
  for (int pos = s0; pos < s1; pos += 64) {
    const int cnt = min(64, s1 - pos);
    __syncthreads();
    if (t < cnt) { ss[t] = bsrc[pos + t]; sw[t] = bw[pos + t]; }
    __syncthreads();
    int j = 0;
    for (; j + 3 < cnt; j += 4) {
      const float x0 = bfu2f(x[ss[j + 0] + t]);
      const float x1 = bfu2f(x[ss[j + 1] + t]);
      const float x2 = bfu2f(x[ss[j + 2] + t]);
      const float x3 = bfu2f(x[ss[j + 3] + t]);
      acc = fmaf(x0, sw[j + 0], acc);
      acc = fmaf(x1, sw[j + 1], acc);
      acc = fmaf(x2, sw[j + 2], acc);
      acc = fmaf(x3, sw[j + 3], acc);
    }
    for (; j < cnt; ++j) acc = fmaf(bfu2f(x[ss[j] + t]), sw[j], acc);
  }
  aggbf[(size_t)n * GNN_C + t] = f2bfu(acc);
}

// restricted aggregation over fp32 x1 (tiny: ~16K edges), bf16 out
__global__ __launch_bounds__(256) void agg_sel_kernel(const int* __restrict__ node_idx,
                                                      const int* __restrict__ bsrc,
                                                      const float* __restrict__ bw,
                                                      const int* __restrict__ off,
                                                      const float* __restrict__ x,
                                                      unsigned short* __restrict__ aggbf) {
  __shared__ int ss[64];
  __shared__ float sw[64];
  const int b = blockIdx.x;
  const int t = threadIdx.x;
  const int n = max(node_idx[b], 0);
  const int s0 = off[n], s1 = off[n + 1];
  float acc = 0.f;
  for (int pos = s0; pos < s1; pos += 64) {
    const int cnt = min(64, s1 - pos);
    __syncthreads();
    if (t < cnt) { ss[t] = bsrc[pos + t]; sw[t] = bw[pos + t]; }
    __syncthreads();
    for (int j = 0; j < cnt; ++j) acc = fmaf(x[ss[j] + t], sw[j], acc);
  }
  aggbf[(size_t)b * GNN_C + t] = f2bfu(acc);
}

// ---------------- MFMA bf16 GEMM 128x128 (trunk conv6 + final gene) ----------------

#define MBK 32
#define MLDW 40

__global__ __launch_bounds__(256) void mgemm_kernel(const unsigned short* __restrict__ A,
                                                    const unsigned short* __restrict__ B,
                                                    const float* __restrict__ bias,
                                                    float* __restrict__ C,
                                                    int M, int N, int K, int transB) {
  __shared__ unsigned short As[128][MLDW];
  __shared__ unsigned short Bs[128][MLDW];
  const int t = threadIdx.x;
  const int lane = t & 63;
  const int wave = t >> 6;
  const int r0 = blockIdx.x * 128;
  const int c0 = blockIdx.y * 128;
  const int wm = (wave >> 1) * 64;
  const int wn = (wave & 1) * 64;
  const int lm = lane & 15;
  const int lq = lane >> 4;

  f4v acc[4][4];
  for (int i = 0; i < 4; ++i)
    for (int j = 0; j < 4; ++j)
      for (int r = 0; r < 4; ++r) acc[i][j][r] = 0.f;

  for (int k0 = 0; k0 < K; k0 += MBK) {
    {
      const int row = t >> 1;
      const int kof = (t & 1) * 16;
      const int gr = r0 + row;
      uint4 u0 = make_uint4(0, 0, 0, 0), u1 = u0;
      if (gr < M) {
        const uint4* p = reinterpret_cast<const uint4*>(A + (size_t)gr * K + k0 + kof);
        u0 = p[0]; u1 = p[1];
      }
      *reinterpret_cast<uint4*>(&As[row][kof]) = u0;
      *reinterpret_cast<uint4*>(&As[row][kof + 8]) = u1;
    }
    if (transB) {
      const int row = t >> 1;
      const int kof = (t & 1) * 16;
      const int gn = c0 + row;
      uint4 u0 = make_uint4(0, 0, 0, 0), u1 = u0;
      if (gn < N) {
        const uint4* p = reinterpret_cast<const uint4*>(B + (size_t)gn * K + k0 + kof);
        u0 = p[0]; u1 = p[1];
      }
      *reinterpret_cast<uint4*>(&Bs[row][kof]) = u0;
      *reinterpret_cast<uint4*>(&Bs[row][kof + 8]) = u1;
    } else {
      const int n = t & 127;
      const int kb = (t >> 7) * 16;
      const int gn = c0 + n;
      union { unsigned short s[16]; uint4 q[2]; } tmp;
      if (gn < N) {
        for (int i = 0; i < 16; ++i) tmp.s[i] = B[(size_t)(k0 + kb + i) * N + gn];
      } else {
        for (int i = 0; i < 16; ++i) tmp.s[i] = 0;
      }
      *reinterpret_cast<uint4*>(&Bs[n][kb]) = tmp.q[0];
      *reinterpret_cast<uint4*>(&Bs[n][kb + 8]) = tmp.q[1];
    }
    __syncthreads();

    bf8v a[4], b[4];
#pragma unroll
    for (int i = 0; i < 4; ++i)
      a[i] = *reinterpret_cast<const bf8v*>(&As[wm + i * 16 + lm][lq * 8]);
#pragma unroll
    for (int j = 0; j < 4; ++j)
      b[j] = *reinterpret_cast<const bf8v*>(&Bs[wn + j * 16 + lm][lq * 8]);
#pragma unroll
    for (int i = 0; i < 4; ++i)
#pragma unroll
      for (int j = 0; j < 4; ++j)
        acc[i][j] = __builtin_amdgcn_mfma_f32_16x16x32_bf16(a[i], b[j], acc[i][j], 0, 0, 0);
    __syncthreads();
  }

  for (int ti = 0; ti < 4; ++ti) {
    for (int tj = 0; tj < 4; ++tj) {
      const int col = c0 + wn + tj * 16 + lm;
      if (col >= N) continue;
      const float bv = bias ? bias[col] : 0.f;
      for (int r = 0; r < 4; ++r) {
        const int row = r0 + wm + ti * 16 + lq * 4 + r;
        if (row < M) C[(size_t)row * N + col] = acc[ti][tj][r] + bv;
      }
    }
  }
}

// ---------------- MFMA bf16 GEMM 64x64 with fused epilogue (head) ----------------
// 4 waves (2x2), each wave 32x32 = 2x2 frags of 16x16x32

__global__ __launch_bounds__(256) void mgemm64_kernel(const unsigned short* __restrict__ A,
                                                      const unsigned short* __restrict__ B,
                                                      const float* __restrict__ bias,
                                                      const float* resid,
                                                      float* outF, unsigned short* outB,
                                                      int M, int N, int K, int doGelu) {
  __shared__ unsigned short As[64][MLDW];
  __shared__ unsigned short Bs[64][MLDW];
  const int t = threadIdx.x;
  const int lane = t & 63;
  const int wave = t >> 6;
  const int r0 = blockIdx.x * 64;
  const int c0 = blockIdx.y * 64;
  const int wm = (wave >> 1) * 32;
  const int wn = (wave & 1) * 32;
  const int lm = lane & 15;
  const int lq = lane >> 4;

  f4v acc[2][2];
  for (int i = 0; i < 2; ++i)
    for (int j = 0; j < 2; ++j)
      for (int r = 0; r < 4; ++r) acc[i][j][r] = 0.f;

  for (int k0 = 0; k0 < K; k0 += MBK) {
    // A: thread t -> row t>>2, kof (t&3)*8 (8 bf16 = 16 B)
    {
      const int row = t >> 2;
      const int kof = (t & 3) * 8;
      const int gr = r0 + row;
      uint4 u = make_uint4(0, 0, 0, 0);
      if (gr < M) u = *reinterpret_cast<const uint4*>(A + (size_t)gr * K + k0 + kof);
      *reinterpret_cast<uint4*>(&As[row][kof]) = u;
    }
    // B[k][n] -> Bs[n][k]: thread t -> n = t&63, kb = (t>>6)*8
    {
      const int n = t & 63;
      const int kb = (t >> 6) * 8;
      const int gn = c0 + n;
      union { unsigned short s[8]; uint4 q; } tmp;
      if (gn < N) {
        for (int i = 0; i < 8; ++i) tmp.s[i] = B[(size_t)(k0 + kb + i) * N + gn];
      } else {
        for (int i = 0; i < 8; ++i) tmp.s[i] = 0;
      }
      *reinterpret_cast<uint4*>(&Bs[n][kb]) = tmp.q;
    }
    __syncthreads();

    bf8v a[2], b[2];
#pragma unroll
    for (int i = 0; i < 2; ++i)
      a[i] = *reinterpret_cast<const bf8v*>(&As[wm + i * 16 + lm][lq * 8]);
#pragma unroll
    for (int j = 0; j < 2; ++j)
      b[j] = *reinterpret_cast<const bf8v*>(&Bs[wn + j * 16 + lm][lq * 8]);
#pragma unroll
    for (int i = 0; i < 2; ++i)
#pragma unroll
      for (int j = 0; j < 2; ++j)
        acc[i][j] = __builtin_amdgcn_mfma_f32_16x16x32_bf16(a[i], b[j], acc[i][j], 0, 0, 0);
    __syncthreads();
  }

  for (int ti = 0; ti < 2; ++ti) {
    for (int tj = 0; tj < 2; ++tj) {
      const int col = c0 + wn + tj * 16 + lm;
      if (col >= N) continue;
      const float bv = bias ? bias[col] : 0.f;
      for (int r = 0; r < 4; ++r) {
        const int row = r0 + wm + ti * 16 + lq * 4 + r;
        if (row >= M) continue;
        float v = acc[ti][tj][r] + bv;
        if (doGelu) v = gelu_tanh(v);
        if (resid) v += resid[(size_t)row * N + col];
        if (outF) outF[(size_t)row * N + col] = v;
        else outB[(size_t)row * N + col] = f2bfu(v);
      }
    }
  }
}

// ---------------- LN family ----------------

__global__ __launch_bounds__(256) void postconv6_kernel(const float* __restrict__ y,
                                                        const float* __restrict__ g,
                                                        const float* __restrict__ b,
                                                        const float* __restrict__ frozen,
                                                        float* __restrict__ x1f) {
  __shared__ float sb[4];
  const int n = blockIdx.x, t = threadIdx.x;
  const float v = y[(size_t)n * GNN_C + t];
  float s = v;
  for (int o = 32; o; o >>= 1) s += __shfl_down(s, o, 64);
  if ((t & 63) == 0) sb[t >> 6] = s;
  __syncthreads();
  const float m = (sb[0] + sb[1] + sb[2] + sb[3]) * (1.f / GNN_C);
  __syncthreads();
  const float d = v - m;
  s = d * d;
  for (int o = 32; o; o >>= 1) s += __shfl_down(s, o, 64);
  if ((t & 63) == 0) sb[t >> 6] = s;
  __syncthreads();
  const float rs = rsqrtf((sb[0] + sb[1] + sb[2] + sb[3]) * (1.f / GNN_C) + LN_EPS);
  const float xn = d * rs * g[t] + b[t];
  x1f[(size_t)n * GNN_C + t] = frozen[(size_t)n * GNN_C + t] + fmaxf(xn, 0.f);
}

// x2 = x1[n_b] + relu(ln(y7)) -> bf16
__global__ __launch_bounds__(256) void postconv7_kernel(const float* __restrict__ y,
                                                        const float* __restrict__ g,
                                                        const float* __restrict__ b,
                                                        const int* __restrict__ idx,
                                                        const float* __restrict__ x1f,
                                                        unsigned short* __restrict__ out) {
  __shared__ float sb[4];
  const int bi = blockIdx.x, t = threadIdx.x;
  const int n = max(idx[bi], 0);
  const float v = y[(size_t)bi * GNN_C + t];
  float s = v;
  for (int o = 32; o; o >>= 1) s += __shfl_down(s, o, 64);
  if ((t & 63) == 0) sb[t >> 6] = s;
  __syncthreads();
  const float m = (sb[0] + sb[1] + sb[2] + sb[3]) * (1.f / GNN_C);
  __syncthreads();
  const float d = v - m;
  s = d * d;
  for (int o = 32; o; o >>= 1) s += __shfl_down(s, o, 64);
  if ((t & 63) == 0) sb[t >> 6] = s;
  __syncthreads();
  const float rs = rsqrtf((sb[0] + sb[1] + sb[2] + sb[3]) * (1.f / GNN_C) + LN_EPS);
  const float xn = d * rs * g[t] + b[t];
  out[(size_t)bi * GNN_C + t] = f2bfu(x1f[(size_t)n * GNN_C + t] + fmaxf(xn, 0.f));
}

// h0 = select(idx, nemb, oov); out = bf16(ln(h0)*g+b)  (C=256)
__global__ __launch_bounds__(256) void h0ln_kernel(const float* __restrict__ ne,
                                                   const int* __restrict__ idx,
                                                   const float* __restrict__ oov,
                                                   const float* __restrict__ g,
                                                   const float* __restrict__ b,
                                                   unsigned short* __restrict__ out) {
  __shared__ float sb[4];
  const int bi = blockIdx.x, t = threadIdx.x;
  const float v = (idx[bi] >= 0) ? ne[(size_t)bi * GNN_C + t] : oov[t];
  float s = v;
  for (int o = 32; o; o >>= 1) s += __shfl_down(s, o, 64);
  if ((t & 63) == 0) sb[t >> 6] = s;
  __syncthreads();
  const float m = (sb[0] + sb[1] + sb[2] + sb[3]) * (1.f / GNN_C);
  __syncthreads();
  const float d = v - m;
  s = d * d;
  for (int o = 32; o; o >>= 1) s += __shfl_down(s, o, 64);
  if ((t & 63) == 0) sb[t >> 6] = s;
  __syncthreads();
  const float rs = rsqrtf((sb[0] + sb[1] + sb[2] + sb[3]) * (1.f / GNN_C) + LN_EPS);
  out[(size_t)bi * GNN_C + t] = f2bfu(d * rs * g[t] + b[t]);
}

// ln over C=512 rows -> bf16
__global__ __launch_bounds__(256) void lnbf_kernel(const float* __restrict__ in,
                                                   const float* __restrict__ g,
                                                   const float* __restrict__ b,
                                                   unsigned short* __restrict__ out) {
  __shared__ float sb[4];
  const int r = blockIdx.x, t = threadIdx.x;
  const float v0 = in[(size_t)r * HID_C + t];
  const float v1 = in[(size_t)r * HID_C + t + 256];
  float s = v0 + v1;
  for (int o = 32; o; o >>= 1) s += __shfl_down(s, o, 64);
  if ((t & 63) == 0) sb[t >> 6] = s;
  __syncthreads();
  const float m = (sb[0] + sb[1] + sb[2] + sb[3]) * (1.f / HID_C);
  __syncthreads();
  const float d0 = v0 - m, d1 = v1 - m;
  s = d0 * d0 + d1 * d1;
  for (int o = 32; o; o >>= 1) s += __shfl_down(s, o, 64);
  if ((t & 63) == 0) sb[t >> 6] = s;
  __syncthreads();
  const float rs = rsqrtf((sb[0] + sb[1] + sb[2] + sb[3]) * (1.f / HID_C) + LN_EPS);
  out[(size_t)r * HID_C + t] = f2bfu(d0 * rs * g[t] + b[t]);
  out[(size_t)r * HID_C + t + 256] = f2bfu(d1 * rs * g[t + 256] + b[t + 256]);
}

// ---------------- host ----------------

extern "C" void kernel_launch(void* const* d_in, const int* in_sizes, int n_in,
                              void* d_out, int out_size, void* d_ws, size_t ws_size,
                              hipStream_t stream) {
  const int* node_idx = (const int*)d_in[0];
  const int* e_src = (const int*)d_in[1];
  const int* e_dst = e_src + N_EDGES_C;
  const float* ew = (const float*)d_in[2];
  const float* frozen = (const float*)d_in[3];
  const float* W6 = (const float*)d_in[4];
  const float* b6 = (const float*)d_in[5];
  const float* g6 = (const float*)d_in[6];
  const float* bl6 = (const float*)d_in[7];
  const float* W7 = (const float*)d_in[8];
  const float* b7 = (const float*)d_in[9];
  const float* g7 = (const float*)d_in[10];
  const float* bl7 = (const float*)d_in[11];
  const float* postW = (const float*)d_in[12];
  const float* postb = (const float*)d_in[13];
  const float* oov = (const float*)d_in[14];
  const float* ing = (const float*)d_in[15];
  const float* inb = (const float*)d_in[16];
  const float* projW = (const float*)d_in[17];
  const float* projb = (const float*)d_in[18];
  const float* rbg = (const float*)d_in[19];
  const float* rbb = (const float*)d_in[20];
  const float* rbW1 = (const float*)d_in[21];
  const float* rbb1 = (const float*)d_in[22];
  const float* rbW2 = (const float*)d_in[23];
  const float* rbb2 = (const float*)d_in[24];
  const float* outg = (const float*)d_in[25];
  const float* outb = (const float*)d_in[26];
  const float* bilW = (const float*)d_in[27];
  const float* bilb = (const float*)d_in[28];
  const float* gene = (const float*)d_in[29];
  (void)in_sizes; (void)n_in; (void)out_size; (void)ws_size;

  char* ws = (char*)d_ws;
  size_t o = 0;
  auto alloc = [&](size_t bytes) -> char* {
    char* p = ws + o;
    o += (bytes + 255) & ~(size_t)255;
    return p;
  };
  int* cnt = (int*)alloc((size_t)N_NODES_C * 4);
  int* off = (int*)alloc((size_t)(N_NODES_C + 1) * 4);
  int* cur = (int*)alloc((size_t)N_NODES_C * 4);
  int* bsrc = (int*)alloc((size_t)N_EDGES_C * 4);
  float* bw = (float*)alloc((size_t)N_EDGES_C * 4);
  unsigned short* frozbf = (unsigned short*)alloc((size_t)N_NODES_C * GNN_C * 2);
  unsigned short* agg6bf = (unsigned short*)alloc((size_t)N_NODES_C * GNN_C * 2);
  unsigned short* w6bf = (unsigned short*)alloc((size_t)GNN_C * GNN_C * 2);
  unsigned short* w7bf = (unsigned short*)alloc((size_t)GNN_C * GNN_C * 2);
  unsigned short* postWbf = (unsigned short*)alloc((size_t)GNN_C * GNN_C * 2);
  unsigned short* projWbf = (unsigned short*)alloc((size_t)GNN_C * HID_C * 2);
  unsigned short* bilWbf = (unsigned short*)alloc((size_t)HID_C * NCLS_C * RANK_C * 2);
  char* y6region = alloc((size_t)N_NODES_C * GNN_C * 4);
  float* x1f = (float*)alloc((size_t)N_NODES_C * GNN_C * 4);

  // aliases (live ranges):
  float* y6 = (float*)y6region;                 // live: conv6 gemm -> postconv6
  unsigned short* genebf = frozbf;              // frozbf dead after agg_full
  unsigned short* rbW1bf = (unsigned short*)x1f;// x1f dead after postconv7
  // head buffers carved from y6region (dead after postconv6)
  {
  }
  size_t ho = 0;
  auto halloc = [&](size_t bytes) -> char* {
    char* p = y6region + ho;
    ho += (bytes + 255) & ~(size_t)255;
    return p;
  };
  unsigned short* rbW2bf = (unsigned short*)halloc((size_t)NBLK_C * 4 * HID_C * HID_C * 2);
  unsigned short* agg7bf = (unsigned short*)halloc((size_t)B_C * GNN_C * 2);
  float* y7b = (float*)halloc((size_t)B_C * GNN_C * 4);
  unsigned short* x2bf = (unsigned short*)halloc((size_t)B_C * GNN_C * 2);
  float* nemb = (float*)halloc((size_t)B_C * GNN_C * 4);
  unsigned short* h0lbf = (unsigned short*)halloc((size_t)B_C * GNN_C * 2);
  float* h = (float*)halloc((size_t)B_C * HID_C * 4);
  unsigned short* tbf = (unsigned short*)halloc((size_t)B_C * HID_C * 2);
  unsigned short* ubf = (unsigned short*)halloc((size_t)B_C * 4 * HID_C * 2);
  unsigned short* hlbf = (unsigned short*)halloc((size_t)B_C * HID_C * 2);
  unsigned short* pertbf = (unsigned short*)halloc((size_t)B_C * NCLS_C * RANK_C * 2);

  // CSR build
  (void)hipMemsetAsync(cnt, 0, (size_t)N_NODES_C * 4, stream);
  (void)hipMemsetAsync(cur, 0, (size_t)N_NODES_C * 4, stream);
  const int egrid = (N_EDGES_C + 255) / 256;
  hist_kernel<<<egrid, 256, 0, stream>>>(e_dst, cnt, N_EDGES_C);
  scan_kernel<<<1, 1024, 0, stream>>>(cnt, off, N_NODES_C);
  fill_kernel<<<egrid, 256, 0, stream>>>(e_src, e_dst, ew, off, cur, bsrc, bw, N_EDGES_C);

  // phase A converts: frozen + small weights
  {
    CvtArgs a;
    a.seg[0] = {frozen, frozbf, (long long)N_NODES_C * GNN_C};
    a.seg[1] = {W6, w6bf, GNN_C * GNN_C};
    a.seg[2] = {W7, w7bf, GNN_C * GNN_C};
    a.seg[3] = {postW, postWbf, GNN_C * GNN_C};
    a.seg[4] = {projW, projWbf, GNN_C * HID_C};
    a.seg[5] = {bilW, bilWbf, HID_C * NCLS_C * RANK_C};
    a.nseg = 6;
    multicvt_kernel<<<512, 256, 0, stream>>>(a);
  }

  // conv6 (full graph): bf16 gather + MFMA GEMM
  agg_full_kernel<<<N_NODES_C, 256, 0, stream>>>(bsrc, bw, off, frozbf, agg6bf);
  {
    dim3 g((N_NODES_C + 127) / 128, GNN_C / 128);
    mgemm_kernel<<<g, 256, 0, stream>>>(agg6bf, w6bf, b6, y6, N_NODES_C, GNN_C, GNN_C, 0);
  }
  postconv6_kernel<<<N_NODES_C, 256, 0, stream>>>(y6, g6, bl6, frozen, x1f);
  // y6region free from here (head buffers + rbW2bf)

  // conv7 (only the B gathered nodes)
  agg_sel_kernel<<<B_C, 256, 0, stream>>>(node_idx, bsrc, bw, off, x1f, agg7bf);
  {
    dim3 g(B_C / 64, GNN_C / 64);
    mgemm64_kernel<<<g, 256, 0, stream>>>(agg7bf, w7bf, b7, nullptr, y7b, nullptr,
                                          B_C, GNN_C, GNN_C, 0);
  }
  postconv7_kernel<<<B_C, 256, 0, stream>>>(y7b, g7, bl7, node_idx, x1f, x2bf);
  // x1f free from here (rbW1bf)

  // phase B converts: big head weights + gene
  {
    CvtArgs a;
    a.seg[0] = {rbW1, rbW1bf, (long long)NBLK_C * 4 * HID_C * HID_C};
    a.seg[1] = {rbW2, rbW2bf, (long long)NBLK_C * 4 * HID_C * HID_C};
    a.seg[2] = {gene, genebf, (long long)NGENES_C * RANK_C};
    a.nseg = 3;
    multicvt_kernel<<<1024, 256, 0, stream>>>(a);
  }

  // node_emb = x2 @ post_W + post_b
  {
    dim3 g(B_C / 64, GNN_C / 64);
    mgemm64_kernel<<<g, 256, 0, stream>>>(x2bf, postWbf, postb, nullptr, nemb, nullptr,
                                          B_C, GNN_C, GNN_C, 0);
  }
  h0ln_kernel<<<B_C, 256, 0, stream>>>(nemb, node_idx, oov, ing, inb, h0lbf);

  // proj_in
  {
    dim3 g(B_C / 64, HID_C / 64);
    mgemm64_kernel<<<g, 256, 0, stream>>>(h0lbf, projWbf, projb, nullptr, h, nullptr,
                                          B_C, HID_C, GNN_C, 0);
  }

  // residual blocks
  for (int i = 0; i < NBLK_C; ++i) {
    lnbf_kernel<<<B_C, 256, 0, stream>>>(h, rbg + (size_t)i * HID_C,
                                         rbb + (size_t)i * HID_C, tbf);
    {
      dim3 g(B_C / 64, (4 * HID_C) / 64);
      mgemm64_kernel<<<g, 256, 0, stream>>>(tbf, rbW1bf + (size_t)i * HID_C * 4 * HID_C,
                                            rbb1 + (size_t)i * 4 * HID_C, nullptr,
                                            nullptr, ubf, B_C, 4 * HID_C, HID_C, 1);
    }
    {
      dim3 g(B_C / 64, HID_C / 64);
      mgemm64_kernel<<<g, 256, 0, stream>>>(ubf, rbW2bf + (size_t)i * 4 * HID_C * HID_C,
                                            rbb2 + (size_t)i * HID_C, h,
                                            h, nullptr, B_C, HID_C, 4 * HID_C, 0);
    }
  }

  // out_ln + bilinear (bf16 out feeds gene GEMM directly)
  lnbf_kernel<<<B_C, 256, 0, stream>>>(h, outg, outb, hlbf);
  {
    dim3 g(B_C / 64, (NCLS_C * RANK_C) / 64);
    mgemm64_kernel<<<g, 256, 0, stream>>>(hlbf, bilWbf, bilb, nullptr,
                                          nullptr, pertbf, B_C, NCLS_C * RANK_C, HID_C, 0);
  }

  // logits = pert[768,512] @ gene^T -> d_out fp32
  {
    dim3 g((B_C * NCLS_C) / 128, (NGENES_C + 127) / 128);
    mgemm_kernel<<<g, 256, 0, stream>>>(pertbf, genebf, nullptr, (float*)d_out,
                                        B_C * NCLS_C, NGENES_C, RANK_C, 1);
  }
}